// Round 5
// baseline (6501.210 us; speedup 1.0000x reference)
//
#include <hip/hip_runtime.h>
#include <hip/hip_bf16.h>
#include <stdint.h>

#define HH   512
#define VV   32000
#define T1N  128
#define T2N  64
#define BB   32
#define NW   6          // recurrence workers (single XCD)

typedef __attribute__((ext_vector_type(8))) short short8;
typedef __attribute__((ext_vector_type(4))) float f32x4;

__device__ __forceinline__ ushort f2b(float f) {
  unsigned u = __float_as_uint(f);
  unsigned r = (u + 0x7fffu + ((u >> 16) & 1u)) >> 16;
  return (ushort)r;
}
__device__ __forceinline__ float blo(unsigned u){ return __uint_as_float(u << 16); }
__device__ __forceinline__ float bhi(unsigned u){ return __uint_as_float(u & 0xffff0000u); }

__device__ __forceinline__ float fast_tanh(float x) {
  float ax = fabsf(x);
  float e  = __expf(-2.f * ax);
  float t  = (1.f - e) / (1.f + e);
  return x < 0.f ? -t : t;
}
__device__ __forceinline__ float fsig(float x) { return 1.f / (1.f + __expf(-x)); }

// ---------------- conversions ----------------
__global__ __launch_bounds__(256) void k_cvt(const float* __restrict__ s, ushort* __restrict__ d, int n) {
  int i = (blockIdx.x * 256 + threadIdx.x) * 4;
  if (i < n) {
    float4 v = *(const float4*)(s + i);
    ushort4 o = { f2b(v.x), f2b(v.y), f2b(v.z), f2b(v.w) };
    *(ushort4*)(d + i) = o;
  }
}

// wa_W (512,1024) -> WxB = wa_W[:, :512], WeB = wa_W[:, 512:]
__global__ __launch_bounds__(256) void k_cvt_wa(const float* __restrict__ wa,
                                                ushort* __restrict__ Wx, ushort* __restrict__ We) {
  int i = (blockIdx.x * 256 + threadIdx.x) * 4;
  int half = (i >= HH * HH);
  int j = i & (HH * HH - 1);
  int o = j >> 9, c = j & 511;
  const float* s = wa + (size_t)o * 1024 + c + (half ? 512 : 0);
  float4 v = *(const float4*)s;
  ushort4 ov = { f2b(v.x), f2b(v.y), f2b(v.z), f2b(v.w) };
  *(ushort4*)((half ? We : Wx) + j) = ov;
}

// x = emb[toks] -> bf16 into ginB[:, 0:512] (row stride 1024)
__global__ __launch_bounds__(256) void k_embed(const int* __restrict__ toks, const float* __restrict__ emb,
                                               ushort* __restrict__ ginB) {
  int i = (blockIdx.x * 256 + threadIdx.x) * 4;
  int row = i >> 9, c = i & 511;
  int tok = toks[row];
  float4 v = *(const float4*)(emb + (size_t)tok * HH + c);
  ushort4 ov = { f2b(v.x), f2b(v.y), f2b(v.z), f2b(v.w) };
  *(ushort4*)(ginB + (size_t)row * 1024 + c) = ov;
}

// ---------------- bf16 MFMA GEMM (fp32 out) ----------------
__global__ __launch_bounds__(256) void k_gemm(const ushort* __restrict__ A, int lda,
                                              const ushort* __restrict__ B,
                                              const float* __restrict__ bias,
                                              float* __restrict__ C, int ldc, int K) {
  __shared__ ushort sA[128 * 32];
  __shared__ ushort sB[128 * 32];
  const int tid  = threadIdx.x;
  const int bm   = blockIdx.y * 128;
  const int bn   = blockIdx.x * 128;
  const int lane = tid & 63;
  const int wave = tid >> 6;
  const int wm   = (wave >> 1) * 64;
  const int wn   = (wave & 1) * 64;
  const int m16  = lane & 15;
  const int quad = lane >> 4;

  f32x4 acc[4][4] = {};

  for (int k0 = 0; k0 < K; k0 += 32) {
#pragma unroll
    for (int q = 0; q < 2; ++q) {
      int idx = q * 256 + tid;
      int row = idx >> 2;
      int kc  = (idx & 3) << 3;
      uint4 va = *(const uint4*)(A + (size_t)(bm + row) * lda + k0 + kc);
      *(uint4*)(&sA[idx * 8]) = va;
      uint4 vb = *(const uint4*)(B + (size_t)(bn + row) * K + k0 + kc);
      *(uint4*)(&sB[idx * 8]) = vb;
    }
    __syncthreads();
    short8 a[4], b[4];
#pragma unroll
    for (int i = 0; i < 4; ++i)
      a[i] = *(const short8*)(&sA[(wm + i * 16 + m16) * 32 + quad * 8]);
#pragma unroll
    for (int j = 0; j < 4; ++j)
      b[j] = *(const short8*)(&sB[(wn + j * 16 + m16) * 32 + quad * 8]);
#pragma unroll
    for (int i = 0; i < 4; ++i)
#pragma unroll
      for (int j = 0; j < 4; ++j)
        acc[i][j] = __builtin_amdgcn_mfma_f32_16x16x32_bf16(a[i], b[j], acc[i][j], 0, 0, 0);
    __syncthreads();
  }
#pragma unroll
  for (int i = 0; i < 4; ++i) {
    int gm = bm + wm + i * 16 + quad * 4;
#pragma unroll
    for (int j = 0; j < 4; ++j) {
      int gn = bn + wn + j * 16 + m16;
      float bv = bias ? bias[gn] : 0.f;
#pragma unroll
      for (int r = 0; r < 4; ++r)
        C[(size_t)(gm + r) * ldc + gn] = acc[i][j][r] + bv;
    }
  }
}

// same GEMM but bf16 output (for gi0)
__global__ __launch_bounds__(256) void k_gemm_b16(const ushort* __restrict__ A, int lda,
                                                  const ushort* __restrict__ B,
                                                  const float* __restrict__ bias,
                                                  ushort* __restrict__ C, int ldc, int K) {
  __shared__ ushort sA[128 * 32];
  __shared__ ushort sB[128 * 32];
  const int tid  = threadIdx.x;
  const int bm   = blockIdx.y * 128;
  const int bn   = blockIdx.x * 128;
  const int lane = tid & 63;
  const int wave = tid >> 6;
  const int wm   = (wave >> 1) * 64;
  const int wn   = (wave & 1) * 64;
  const int m16  = lane & 15;
  const int quad = lane >> 4;

  f32x4 acc[4][4] = {};

  for (int k0 = 0; k0 < K; k0 += 32) {
#pragma unroll
    for (int q = 0; q < 2; ++q) {
      int idx = q * 256 + tid;
      int row = idx >> 2;
      int kc  = (idx & 3) << 3;
      uint4 va = *(const uint4*)(A + (size_t)(bm + row) * lda + k0 + kc);
      *(uint4*)(&sA[idx * 8]) = va;
      uint4 vb = *(const uint4*)(B + (size_t)(bn + row) * K + k0 + kc);
      *(uint4*)(&sB[idx * 8]) = vb;
    }
    __syncthreads();
    short8 a[4], b[4];
#pragma unroll
    for (int i = 0; i < 4; ++i)
      a[i] = *(const short8*)(&sA[(wm + i * 16 + m16) * 32 + quad * 8]);
#pragma unroll
    for (int j = 0; j < 4; ++j)
      b[j] = *(const short8*)(&sB[(wn + j * 16 + m16) * 32 + quad * 8]);
#pragma unroll
    for (int i = 0; i < 4; ++i)
#pragma unroll
      for (int j = 0; j < 4; ++j)
        acc[i][j] = __builtin_amdgcn_mfma_f32_16x16x32_bf16(a[i], b[j], acc[i][j], 0, 0, 0);
    __syncthreads();
  }
#pragma unroll
  for (int i = 0; i < 4; ++i) {
    int gm = bm + wm + i * 16 + quad * 4;
#pragma unroll
    for (int j = 0; j < 4; ++j) {
      int gn = bn + wn + j * 16 + m16;
      float bv = bias ? bias[gn] : 0.f;
#pragma unroll
      for (int r = 0; r < 4; ++r)
        C[(size_t)(gm + r) * ldc + gn] = f2b(acc[i][j][r] + bv);
    }
  }
}

// ---------------- attention ----------------
__global__ __launch_bounds__(256) void k_scores(const float* __restrict__ xproj,
                                                const float* __restrict__ encp,
                                                const float* __restrict__ vaW,
                                                float* __restrict__ e) {
  int t2g = blockIdx.x >> 5;
  int b   = blockIdx.x & 31;
  __shared__ float sx[4][512];
  int tid = threadIdx.x;
  for (int i = tid; i < 4 * 512; i += 256) {
    int tt = i >> 9, h = i & 511;
    sx[tt][h] = xproj[((size_t)(t2g * 4 + tt) * BB + b) * HH + h];
  }
  __syncthreads();
  int lane = tid & 63, w = tid >> 6;
  int h8 = lane * 8;
  float va[8];
#pragma unroll
  for (int j = 0; j < 8; ++j) va[j] = vaW[h8 + j];
  for (int t1 = w; t1 < T1N; t1 += 4) {
    const float* ep = encp + ((size_t)t1 * BB + b) * HH + h8;
    float ev[8];
    *(float4*)&ev[0] = *(const float4*)ep;
    *(float4*)&ev[4] = *(const float4*)(ep + 4);
    float s0 = 0, s1 = 0, s2 = 0, s3 = 0;
#pragma unroll
    for (int j = 0; j < 8; ++j) {
      float epj = ev[j], vj = va[j];
      s0 += fast_tanh(sx[0][h8 + j] + epj) * vj;
      s1 += fast_tanh(sx[1][h8 + j] + epj) * vj;
      s2 += fast_tanh(sx[2][h8 + j] + epj) * vj;
      s3 += fast_tanh(sx[3][h8 + j] + epj) * vj;
    }
#pragma unroll
    for (int off = 32; off; off >>= 1) {
      s0 += __shfl_down(s0, off);
      s1 += __shfl_down(s1, off);
      s2 += __shfl_down(s2, off);
      s3 += __shfl_down(s3, off);
    }
    if (lane == 0) {
      size_t base = ((size_t)(t2g * 4) * BB + b) * T1N + t1;
      e[base]                 = s0;
      e[base + 1 * BB * T1N]  = s1;
      e[base + 2 * BB * T1N]  = s2;
      e[base + 3 * BB * T1N]  = s3;
    }
  }
}

__global__ __launch_bounds__(128) void k_softmax(const float* __restrict__ e, float* __restrict__ score,
                                                 float* __restrict__ out_last) {
  int row = blockIdx.x;
  int tid = threadIdx.x;
  float v = e[(size_t)row * T1N + tid];
  __shared__ float red[128];
  red[tid] = v; __syncthreads();
  for (int s = 64; s; s >>= 1) { if (tid < s) red[tid] = fmaxf(red[tid], red[tid + s]); __syncthreads(); }
  float mx = red[0]; __syncthreads();
  float p = __expf(v - mx);
  red[tid] = p; __syncthreads();
  for (int s = 64; s; s >>= 1) { if (tid < s) red[tid] += red[tid + s]; __syncthreads(); }
  float sc = p / red[0];
  score[(size_t)row * T1N + tid] = sc;
  if ((row >> 5) == T2N - 1) out_last[tid * BB + (row & 31)] = sc;
}

__global__ __launch_bounds__(256) void k_attv(const float* __restrict__ enc, const float* __restrict__ score,
                                              ushort* __restrict__ ginB) {
  int t2g = blockIdx.x >> 5;
  int b   = blockIdx.x & 31;
  __shared__ float ssc[8][T1N];
  int tid = threadIdx.x;
  for (int i = tid; i < 8 * T1N; i += 256) {
    int j = i >> 7, t1 = i & 127;
    ssc[j][t1] = score[((size_t)(t2g * 8 + j) * BB + b) * T1N + t1];
  }
  __syncthreads();
  float a0[8] = {}, a1[8] = {};
  for (int t1 = 0; t1 < T1N; ++t1) {
    const float* er = enc + ((size_t)t1 * BB + b) * HH;
    float e0 = er[tid], e1 = er[tid + 256];
#pragma unroll
    for (int j = 0; j < 8; ++j) { a0[j] += e0 * ssc[j][t1]; a1[j] += e1 * ssc[j][t1]; }
  }
#pragma unroll
  for (int j = 0; j < 8; ++j) {
    size_t r = (size_t)(t2g * 8 + j) * BB + b;
    ginB[r * 1024 + 512 + tid]       = f2b(a0[j]);
    ginB[r * 1024 + 512 + tid + 256] = f2b(a1[j]);
  }
}

// ---------------- persistent single-XCD recurrence ----------------
// GRU elementwise pair helper
__device__ __forceinline__ void gru_pair(uint gr, uint gz, uint gn, uint hr, uint hz, uint hn,
                                         float hold0, float hold1, float& o0, float& o1) {
  float r0 = fsig(blo(gr) + blo(hr));
  float r1 = fsig(bhi(gr) + bhi(hr));
  float z0 = fsig(blo(gz) + blo(hz));
  float z1 = fsig(bhi(gz) + bhi(hz));
  float n0 = fast_tanh(blo(gn) + r0 * blo(hn));
  float n1 = fast_tanh(bhi(gn) + r1 * bhi(hn));
  o0 = (1.f - z0) * n0 + z0 * hold0;
  o1 = (1.f - z1) * n1 + z1 * hold1;
}

// Agent-scope relaxed RMW: executes at the coherence point; used for all
// barrier/census counters so visibility never depends on cache state.
__device__ __forceinline__ unsigned armw(unsigned* p, unsigned v) {
  return __hip_atomic_fetch_add(p, v, __ATOMIC_RELAXED, __HIP_MEMORY_SCOPE_AGENT);
}

#define SPIN_GE(addr, target)                                             \
  {                                                                       \
    unsigned long long _t0 = __builtin_amdgcn_s_memrealtime();            \
    while (armw((addr), 0u) < (target)) {                                 \
      __builtin_amdgcn_s_sleep(1);                                        \
      if (__builtin_amdgcn_s_memrealtime() - _t0 > 5000000ull) break;     \
    }                                                                     \
  }

// Same-XCD worker barrier. All NW workers share one L2: vector L1 is
// write-through on CDNA (stores are in L2 once vmcnt drains), so NO
// wbl2/invl2 is needed -- only an L1 invalidate on the consume side.
__device__ __forceinline__ void wbar(unsigned* cnt, unsigned ep) {
  __syncthreads();                                  // vmcnt drained: stores in L2
  if (threadIdx.x == 0) {
    armw(cnt, 1u);
    SPIN_GE(cnt, NW * ep);
    asm volatile("s_waitcnt vmcnt(0)\n\tbuffer_inv sc0\n\ts_waitcnt vmcnt(0)" ::: "memory");
  }
  __syncthreads();
}

__global__ void k_bar_init(unsigned* bs) {
  for (int i = threadIdx.x; i < 512; i += 256) bs[i] = 0u;
}

struct RecurP {
  const ushort* Whh0B; const ushort* Whh1B; const ushort* Wih1B;
  const float* bhh0; const float* bhh1; const float* bih1;
  const ushort* gi0B;
  const float* state;     // (2,B,H) fp32
  const ushort* stateB;   // bf16 h0 init
  ushort* gh0x;
  ushort* gh1b0; ushort* gh1b1;
  ushort* gi1x;
  float* h0f;             // per-worker private fp32 h0 carry [NW][B*H]
  float* h1f;             // per-worker private fp32 h1 carry [NW][B*H]
  float* h_out;           // d_out h section (2,B,H)
  ushort* ysB;            // (T2N,B,H) bf16
  unsigned* bar;          // barrier state (512 uints, zeroed)
};

// 48 blocks launch; census elects NW=6 workers on ONE XCD (pigeonhole:
// 48 blocks / 8 XCDs guarantees an XCD with >=6). Others exit. All
// producer/consumer traffic stays inside that XCD's L2 -> no cross-XCD
// coherence ops, ~1-2us barriers instead of ~16us.
__global__ __launch_bounds__(256, 1) void k_recur(RecurP p) {
  __shared__ ushort sH1[32 * 520];   // h1(t-1) bf16 (full batch)
  __shared__ ushort sH0[32 * 520];   // h0 bf16 (full batch)
  const int tid  = threadIdx.x;
  const int lane = tid & 63, wave = tid >> 6;
  const int bt = wave & 1;           // batch half (16 rows)
  const int nh = wave >> 1;          // n-half (128 rows)
  const int m16 = lane & 15, quad = lane >> 4;
  const int k0 = tid * 2;
  unsigned* bs = p.bar;
  const float* state1 = p.state + BB * HH;

  // ---- census: find an XCD with >= NW blocks; first NW ranks are workers ----
  unsigned xcc;
  asm volatile("s_getreg_b32 %0, hwreg(HW_REG_XCC_ID)" : "=s"(xcc));
  xcc &= 7u;
  __shared__ int s_wid;
  if (tid == 0) {
    unsigned rank = armw(bs + xcc * 16, 1u);
    armw(bs + 128, 1u);
    SPIN_GE(bs + 128, gridDim.x);
    int chosen = -1;
    for (int i = 0; i < 8; ++i)
      if (chosen < 0 && armw(bs + (unsigned)i * 16, 0u) >= (unsigned)NW) chosen = i;
    s_wid = (chosen == (int)xcc && rank < (unsigned)NW) ? (int)rank : -1;
  }
  __syncthreads();
  const int wid = s_wid;
  if (wid < 0) return;               // non-workers exit

  float* h0f = p.h0f + (size_t)wid * (BB * HH);
  float* h1f = p.h1f + (size_t)wid * (BB * HH);
  const int browA = bt * 16 + quad * 4;
  unsigned* cnt = bs + 144;

#pragma unroll 1
  for (int t = 0; t < T2N; ++t) {
    const int par = t & 1;
    // ---------------- phase A: h1(t-1) GRU + gh0/gh1 GEMM ----------------
    if (t == 0) {
      for (int i = tid; i < 16384; i += 256) {
        int b = i >> 9, k = i & 511;
        sH1[b * 520 + k] = f2b(state1[i]);
        sH0[b * 520 + k] = p.stateB[i];
      }
    } else {
      const ushort* gh1in = par ? p.gh1b0 : p.gh1b1;              // gh1buf[(t+1)&1]
      const float*  h1hold = (t == 1) ? state1 : h1f;
      ushort* ysprev = p.ysB + (size_t)(t - 1) * BB * HH;
#pragma unroll 4
      for (int b = 0; b < 32; ++b) {
        const ushort* gi = p.gi1x + b * 1536 + k0;
        const ushort* gh = gh1in + b * 1536 + k0;
        uint gir = *(const uint*)(gi);
        uint giz = *(const uint*)(gi + 512);
        uint gin = *(const uint*)(gi + 1024);
        uint hr  = *(const uint*)(gh);
        uint hz  = *(const uint*)(gh + 512);
        uint hn  = *(const uint*)(gh + 1024);
        float2 hold = *(const float2*)(h1hold + b * 512 + k0);
        float o0, o1;
        gru_pair(gir, giz, gin, hr, hz, hn, hold.x, hold.y, o0, o1);
        uint hb = (uint)f2b(o0) | ((uint)f2b(o1) << 16);
        *(uint*)(&sH1[b * 520 + k0]) = hb;
        *(float2*)(h1f + b * 512 + k0) = make_float2(o0, o1);
        if ((b % NW) == wid) *(uint*)(ysprev + b * 512 + k0) = hb;
      }
    }
    __syncthreads();

    {
      ushort* gh1out = par ? p.gh1b1 : p.gh1b0;                   // gh1buf[t&1]
      // gh0 = h0(t-1) @ Whh0^T : A from sH0
      short8 ar[16];
#pragma unroll
      for (int kc = 0; kc < 16; ++kc)
        ar[kc] = *(const short8*)(&sH0[(bt * 16 + m16) * 520 + kc * 32 + quad * 8]);
#pragma unroll 2
      for (int i8 = 0; i8 < 8; ++i8) {
        int nr = wid * 256 + nh * 128 + i8 * 16 + m16;
        const ushort* Br = p.Whh0B + (size_t)nr * 512 + quad * 8;
        f32x4 acc = {0.f, 0.f, 0.f, 0.f};
#pragma unroll
        for (int kc = 0; kc < 16; ++kc)
          acc = __builtin_amdgcn_mfma_f32_16x16x32_bf16(ar[kc], *(const short8*)(Br + kc * 32), acc, 0, 0, 0);
        float bv = p.bhh0[nr];
#pragma unroll
        for (int r = 0; r < 4; ++r)
          p.gh0x[(browA + r) * 1536 + nr] = f2b(acc[r] + bv);
      }
      // gh1 = h1(t-1) @ Whh1^T : A from sH1
#pragma unroll
      for (int kc = 0; kc < 16; ++kc)
        ar[kc] = *(const short8*)(&sH1[(bt * 16 + m16) * 520 + kc * 32 + quad * 8]);
#pragma unroll 2
      for (int i8 = 0; i8 < 8; ++i8) {
        int nr = wid * 256 + nh * 128 + i8 * 16 + m16;
        const ushort* Br = p.Whh1B + (size_t)nr * 512 + quad * 8;
        f32x4 acc = {0.f, 0.f, 0.f, 0.f};
#pragma unroll
        for (int kc = 0; kc < 16; ++kc)
          acc = __builtin_amdgcn_mfma_f32_16x16x32_bf16(ar[kc], *(const short8*)(Br + kc * 32), acc, 0, 0, 0);
        float bv = p.bhh1[nr];
#pragma unroll
        for (int r = 0; r < 4; ++r)
          gh1out[(browA + r) * 1536 + nr] = f2b(acc[r] + bv);
      }
    }
    wbar(cnt, (unsigned)(2 * t + 1));

    // ---------------- phase B: h0(t) GRU + gi1 GEMM ----------------
    {
      const ushort* gi0t = p.gi0B + (size_t)t * 32 * 1536;
      const float* h0hold = (t == 0) ? p.state : h0f;
#pragma unroll 4
      for (int b = 0; b < 32; ++b) {
        const ushort* gi = gi0t + b * 1536 + k0;
        const ushort* gh = p.gh0x + b * 1536 + k0;
        uint gir = *(const uint*)(gi);
        uint giz = *(const uint*)(gi + 512);
        uint gin = *(const uint*)(gi + 1024);
        uint hr  = *(const uint*)(gh);
        uint hz  = *(const uint*)(gh + 512);
        uint hn  = *(const uint*)(gh + 1024);
        float2 hold = *(const float2*)(h0hold + b * 512 + k0);
        float o0, o1;
        gru_pair(gir, giz, gin, hr, hz, hn, hold.x, hold.y, o0, o1);
        uint hb = (uint)f2b(o0) | ((uint)f2b(o1) << 16);
        *(uint*)(&sH0[b * 520 + k0]) = hb;
        *(float2*)(h0f + b * 512 + k0) = make_float2(o0, o1);
      }
      __syncthreads();

      short8 ar[16];
#pragma unroll
      for (int kc = 0; kc < 16; ++kc)
        ar[kc] = *(const short8*)(&sH0[(bt * 16 + m16) * 520 + kc * 32 + quad * 8]);
#pragma unroll 2
      for (int i8 = 0; i8 < 8; ++i8) {
        int nr = wid * 256 + nh * 128 + i8 * 16 + m16;
        const ushort* Br = p.Wih1B + (size_t)nr * 512 + quad * 8;
        f32x4 acc = {0.f, 0.f, 0.f, 0.f};
#pragma unroll
        for (int kc = 0; kc < 16; ++kc)
          acc = __builtin_amdgcn_mfma_f32_16x16x32_bf16(ar[kc], *(const short8*)(Br + kc * 32), acc, 0, 0, 0);
        float bv = p.bih1[nr];
#pragma unroll
        for (int r = 0; r < 4; ++r)
          p.gi1x[(browA + r) * 1536 + nr] = f2b(acc[r] + bv);
      }
    }
    wbar(cnt, (unsigned)(2 * t + 2));
  }

  // ---------------- final: h1(63), ys[63], out_h ----------------
  for (int b = wid; b < 32; b += NW) {
    const ushort* gi = p.gi1x + b * 1536 + k0;
    const ushort* gh = p.gh1b1 + b * 1536 + k0;   // gh1buf[63&1] = gh1buf[1]
    uint gir = *(const uint*)(gi);
    uint giz = *(const uint*)(gi + 512);
    uint gin = *(const uint*)(gi + 1024);
    uint hr  = *(const uint*)(gh);
    uint hz  = *(const uint*)(gh + 512);
    uint hn  = *(const uint*)(gh + 1024);
    float2 hold = *(const float2*)(h1f + b * 512 + k0);  // h1(62)
    float o0, o1;
    gru_pair(gir, giz, gin, hr, hz, hn, hold.x, hold.y, o0, o1);
    *(uint*)(p.ysB + (size_t)63 * BB * HH + b * 512 + k0) = (uint)f2b(o0) | ((uint)f2b(o1) << 16);
    p.h_out[16384 + b * 512 + k0]     = o0;
    p.h_out[16384 + b * 512 + k0 + 1] = o1;
    float2 h0p = *(const float2*)(h0f + b * 512 + k0);   // h0(63)
    *(float2*)(p.h_out + b * 512 + k0) = h0p;
  }
}

// ---------------- launch ----------------
extern "C" void kernel_launch(void* const* d_in, const int* in_sizes, int n_in,
                              void* d_out, int out_size, void* d_ws, size_t ws_size,
                              hipStream_t stream) {
  const int*   toks  = (const int*)d_in[0];
  const float* state = (const float*)d_in[1];
  const float* enc   = (const float*)d_in[2];
  const float* emb   = (const float*)d_in[3];
  const float* wa_W  = (const float*)d_in[4];
  const float* wa_b  = (const float*)d_in[5];
  const float* va    = (const float*)d_in[6];
  const float* b_ih0 = (const float*)d_in[9];
  const float* b_hh0 = (const float*)d_in[10];
  const float* b_ih1 = (const float*)d_in[13];
  const float* b_hh1 = (const float*)d_in[14];
  const float* out_W = (const float*)d_in[15];
  const float* out_b = (const float*)d_in[16];
  const float* W_ih0 = (const float*)d_in[7];
  const float* W_hh0 = (const float*)d_in[8];
  const float* W_ih1 = (const float*)d_in[11];
  const float* W_hh1 = (const float*)d_in[12];

  float* y_out  = (float*)d_out;
  float* h_out  = y_out + (size_t)T2N * BB * VV;
  float* ls_out = h_out + 2 * BB * HH;

  char* ws = (char*)d_ws;
  size_t off = 0;
  auto alloc = [&](size_t bytes) -> void* {
    void* p = ws + off;
    off += (bytes + 255) & ~(size_t)255;
    return p;
  };
  ushort* encB   = (ushort*)alloc((size_t)T1N * BB * HH * 2);
  ushort* ginB   = (ushort*)alloc((size_t)T2N * BB * 2 * HH * 2);
  ushort* WeB    = (ushort*)alloc((size_t)HH * HH * 2);
  ushort* WxB    = (ushort*)alloc((size_t)HH * HH * 2);
  ushort* Wih0B  = (ushort*)alloc((size_t)3 * HH * 2 * HH * 2);
  ushort* Whh0B  = (ushort*)alloc((size_t)3 * HH * HH * 2);
  ushort* Wih1B  = (ushort*)alloc((size_t)3 * HH * HH * 2);
  ushort* Whh1B  = (ushort*)alloc((size_t)3 * HH * HH * 2);
  ushort* outWB  = (ushort*)alloc((size_t)VV * HH * 2);
  ushort* stateB = (ushort*)alloc((size_t)BB * HH * 2);
  float* encproj = (float*)alloc((size_t)T1N * BB * HH * 4);
  float* xproj   = (float*)alloc((size_t)T2N * BB * HH * 4);
  float* eM      = (float*)alloc((size_t)T2N * BB * T1N * 4);
  float* score   = (float*)alloc((size_t)T2N * BB * T1N * 4);
  ushort* gi0B   = (ushort*)alloc((size_t)T2N * BB * 3 * HH * 2);
  ushort* gh0x   = (ushort*)alloc((size_t)BB * 3 * HH * 2);
  ushort* gh1buf0 = (ushort*)alloc((size_t)BB * 3 * HH * 2);
  ushort* gh1buf1 = (ushort*)alloc((size_t)BB * 3 * HH * 2);
  ushort* gi1x   = (ushort*)alloc((size_t)BB * 3 * HH * 2);
  float* h0fw    = (float*)alloc((size_t)NW * BB * HH * 4);
  float* h1fw    = (float*)alloc((size_t)NW * BB * HH * 4);
  ushort* ysB    = (ushort*)alloc((size_t)T2N * BB * HH * 2);
  unsigned* bar  = (unsigned*)alloc(2048);

  // preamble
  k_bar_init<<<1, 256, 0, stream>>>(bar);
  k_cvt<<<VV * HH / 1024, 256, 0, stream>>>(out_W, outWB, VV * HH);
  k_cvt<<<T1N * BB * HH / 1024, 256, 0, stream>>>(enc, encB, T1N * BB * HH);
  k_cvt<<<3 * HH * 2 * HH / 1024, 256, 0, stream>>>(W_ih0, Wih0B, 3 * HH * 2 * HH);
  k_cvt<<<3 * HH * HH / 1024, 256, 0, stream>>>(W_hh0, Whh0B, 3 * HH * HH);
  k_cvt<<<3 * HH * HH / 1024, 256, 0, stream>>>(W_ih1, Wih1B, 3 * HH * HH);
  k_cvt<<<3 * HH * HH / 1024, 256, 0, stream>>>(W_hh1, Whh1B, 3 * HH * HH);
  k_cvt<<<BB * HH / 1024, 256, 0, stream>>>(state, stateB, BB * HH);
  k_cvt_wa<<<2 * HH * HH / 1024, 256, 0, stream>>>(wa_W, WxB, WeB);
  k_embed<<<T2N * BB * HH / 1024, 256, 0, stream>>>(toks, emb, ginB);

  k_gemm<<<dim3(HH / 128, T1N * BB / 128), 256, 0, stream>>>(encB, HH, WeB, wa_b, encproj, HH, HH);
  k_gemm<<<dim3(HH / 128, T2N * BB / 128), 256, 0, stream>>>(ginB, 2 * HH, WxB, nullptr, xproj, HH, HH);

  k_scores<<<512, 256, 0, stream>>>(xproj, encproj, va, eM);
  k_softmax<<<T2N * BB, 128, 0, stream>>>(eM, score, ls_out);
  k_attv<<<256, 256, 0, stream>>>(enc, score, ginB);

  k_gemm_b16<<<dim3(3 * HH / 128, T2N * BB / 128), 256, 0, stream>>>(ginB, 2 * HH, Wih0B, b_ih0, gi0B, 3 * HH, 2 * HH);

  // recurrence: persistent cooperative kernel, single-XCD worker set
  RecurP rp;
  rp.Whh0B = Whh0B; rp.Whh1B = Whh1B; rp.Wih1B = Wih1B;
  rp.bhh0 = b_hh0; rp.bhh1 = b_hh1; rp.bih1 = b_ih1;
  rp.gi0B = gi0B;
  rp.state = state; rp.stateB = stateB;
  rp.gh0x = gh0x;
  rp.gh1b0 = gh1buf0; rp.gh1b1 = gh1buf1;
  rp.gi1x = gi1x;
  rp.h0f = h0fw; rp.h1f = h1fw;
  rp.h_out = h_out; rp.ysB = ysB;
  rp.bar = bar;
  void* kargs[] = { &rp };
  hipLaunchCooperativeKernel((const void*)k_recur, dim3(48), dim3(256), kargs, 0, stream);

  // y = ys @ out_W^T + out_b
  k_gemm<<<dim3(VV / 128, T2N * BB / 128), 256, 0, stream>>>(ysB, HH, outWB, out_b, y_out, VV, HH);
}